// Round 1
// baseline (579.286 us; speedup 1.0000x reference)
//
#include <hip/hip_runtime.h>
#include <cstddef>

#define NROWS 16384
#define NCOLS 4096
#define NG 32
#define GD 128
#define NP 8
#define ROWS_PER_P (NROWS / NP)  // 2048

// ---------------- K1: partial X^T X + column sums per (group, stripe) ----------
__global__ __launch_bounds__(512) void k_cov_partial(
    const float* __restrict__ x, float* __restrict__ xtx, float* __restrict__ colsum)
{
    __shared__ float As[32][132];
    __shared__ float red[16][128];
    const int bid = blockIdx.x;
    const int g = bid >> 3;
    const int p = bid & 7;
    const int t = threadIdx.x;
    const int tx = t & 15;   // output cols tx*8 .. +7
    const int ty = t >> 4;   // output rows ty*4 .. +3
    const float* xbase = x + (size_t)p * ROWS_PER_P * NCOLS + g * GD;

    float acc[4][8];
#pragma unroll
    for (int r = 0; r < 4; ++r)
#pragma unroll
        for (int c = 0; c < 8; ++c) acc[r][c] = 0.0f;
    float csum[4] = {0.f, 0.f, 0.f, 0.f};

    for (int chunk = 0; chunk < ROWS_PER_P / 32; ++chunk) {
        __syncthreads();
#pragma unroll
        for (int k = 0; k < 2; ++k) {
            int q = t + 512 * k;
            int row = q >> 5, c4 = q & 31;
            float4 v = *(const float4*)(xbase + (size_t)(chunk * 32 + row) * NCOLS + c4 * 4);
            *(float4*)&As[row][c4 * 4] = v;
            csum[0] += v.x; csum[1] += v.y; csum[2] += v.z; csum[3] += v.w;
        }
        __syncthreads();
#pragma unroll 4
        for (int n = 0; n < 32; ++n) {
            float4 a4 = *(const float4*)&As[n][ty * 4];
            float4 b0 = *(const float4*)&As[n][tx * 8];
            float4 b1 = *(const float4*)&As[n][tx * 8 + 4];
            float a_[4] = {a4.x, a4.y, a4.z, a4.w};
            float b_[8] = {b0.x, b0.y, b0.z, b0.w, b1.x, b1.y, b1.z, b1.w};
#pragma unroll
            for (int r = 0; r < 4; ++r)
#pragma unroll
                for (int c = 0; c < 8; ++c) acc[r][c] = fmaf(a_[r], b_[c], acc[r][c]);
        }
    }
    // write partial X^T X
    float* obase = xtx + (size_t)bid * GD * GD;
#pragma unroll
    for (int r = 0; r < 4; ++r) {
        int i = ty * 4 + r;
        *(float4*)(obase + (size_t)i * GD + tx * 8) =
            make_float4(acc[r][0], acc[r][1], acc[r][2], acc[r][3]);
        *(float4*)(obase + (size_t)i * GD + tx * 8 + 4) =
            make_float4(acc[r][4], acc[r][5], acc[r][6], acc[r][7]);
    }
    // reduce column sums across the 16 row-groups of threads
    red[t >> 5][(t & 31) * 4 + 0] = csum[0];
    red[t >> 5][(t & 31) * 4 + 1] = csum[1];
    red[t >> 5][(t & 31) * 4 + 2] = csum[2];
    red[t >> 5][(t & 31) * 4 + 3] = csum[3];
    __syncthreads();
    if (t < 128) {
        float s = 0.f;
#pragma unroll
        for (int r = 0; r < 16; ++r) s += red[r][t];
        colsum[(size_t)bid * GD + t] = s;
    }
}

// ---------------- K2: reduce partials -> cov, Gershgorin scale, Y0/Z0 ----------
__global__ __launch_bounds__(256) void k_covprep(
    const float* __restrict__ xtx, const float* __restrict__ colsum,
    float* __restrict__ mean, float* __restrict__ scale,
    float* __restrict__ Y0, float* __restrict__ Z0)
{
    __shared__ float Cs[128][129];
    __shared__ float mu[128];
    __shared__ float rs[128];
    __shared__ float sinv[1];
    const int g = blockIdx.x;
    const int t = threadIdx.x;

    if (t < 128) {
        float s = 0.f;
#pragma unroll
        for (int p = 0; p < NP; ++p) s += colsum[(size_t)(g * NP + p) * GD + t];
        float m = s * (1.0f / (float)NROWS);
        mu[t] = m;
        mean[g * GD + t] = m;
    }
    __syncthreads();
    for (int k = 0; k < 64; ++k) {
        int e = t + 256 * k;
        int i = e >> 7, j = e & 127;
        float s = 0.f;
#pragma unroll
        for (int p = 0; p < NP; ++p) s += xtx[(size_t)(g * NP + p) * GD * GD + e];
        float cov = (s - (float)NROWS * mu[i] * mu[j]) * (1.0f / (float)(NROWS - 1));
        Cs[i][j] = cov;
    }
    __syncthreads();
    if (t < 128) {  // row sums of |cov| via columns (cov symmetric)
        float s = 0.f;
        for (int i = 0; i < 128; ++i) s += fabsf(Cs[i][t]);
        rs[t] = s;
    }
    __syncthreads();
    if (t == 0) {
        float up = 0.f, lo = 1e30f;
        for (int i = 0; i < 128; ++i) {
            up = fmaxf(up, rs[i]);
            lo = fminf(lo, 2.0f * Cs[i][i] - rs[i]);
        }
        float c = 0.5f * (up + fmaxf(lo, 0.0f));
        c = fmaxf(c, 1e-20f);
        sinv[0] = 1.0f / c;
        scale[g] = rsqrtf(c);
    }
    __syncthreads();
    float invc = sinv[0];
    for (int k = 0; k < 64; ++k) {
        int e = t + 256 * k;
        int i = e >> 7, j = e & 127;
        Y0[(size_t)g * GD * GD + e] = Cs[i][j] * invc;
        Z0[(size_t)g * GD * GD + e] = (i == j) ? 1.0f : 0.0f;
    }
}

// ---------------- K4: one Newton-Schulz iteration, column-sliced ---------------
// Y' = 1.5 Y - 0.5 Y*T ;  Z' = 1.5 Z - 0.5 Z*T ;  T = Z*Y
__global__ __launch_bounds__(256) void k_ns_iter(
    const float* __restrict__ Yin, const float* __restrict__ Zin,
    float* __restrict__ Yout, float* __restrict__ Zout)
{
    __shared__ float Ys[128][132];
    __shared__ float Zs[128][132];
    __shared__ float Ts[128][16];
    const int bid = blockIdx.x;
    const int g = bid >> 3;
    const int sl = bid & 7;
    const int J0 = sl * 16;
    const int t = threadIdx.x;
    const float* Yg = Yin + (size_t)g * GD * GD;
    const float* Zg = Zin + (size_t)g * GD * GD;
#pragma unroll
    for (int k = 0; k < 16; ++k) {
        int q = t + 256 * k;  // float4 index
        int row = q >> 5, c4 = q & 31;
        *(float4*)&Ys[row][c4 * 4] = *(const float4*)(Yg + (size_t)q * 4);
        *(float4*)&Zs[row][c4 * 4] = *(const float4*)(Zg + (size_t)q * 4);
    }
    __syncthreads();
    const int i = t >> 1;
    const int jb = (t & 1) * 8;

    // T[i][J0+jb .. +8) = sum_k Z[i][k] * Y[k][J0+jb..]
    float accT[8];
#pragma unroll
    for (int q = 0; q < 8; ++q) accT[q] = 0.f;
    for (int k4 = 0; k4 < 32; ++k4) {
        float4 zv = *(const float4*)&Zs[i][k4 * 4];
        float zz[4] = {zv.x, zv.y, zv.z, zv.w};
#pragma unroll
        for (int e = 0; e < 4; ++e) {
            const int k = k4 * 4 + e;
            float4 y0 = *(const float4*)&Ys[k][J0 + jb];
            float4 y1 = *(const float4*)&Ys[k][J0 + jb + 4];
            float yy[8] = {y0.x, y0.y, y0.z, y0.w, y1.x, y1.y, y1.z, y1.w};
#pragma unroll
            for (int q = 0; q < 8; ++q) accT[q] = fmaf(zz[e], yy[q], accT[q]);
        }
    }
#pragma unroll
    for (int q = 0; q < 8; ++q) Ts[i][jb + q] = accT[q];
    __syncthreads();

    float ay[8], az[8];
#pragma unroll
    for (int q = 0; q < 8; ++q) { ay[q] = 0.f; az[q] = 0.f; }
    for (int k4 = 0; k4 < 32; ++k4) {
        float4 yv = *(const float4*)&Ys[i][k4 * 4];
        float4 zv = *(const float4*)&Zs[i][k4 * 4];
        float yy[4] = {yv.x, yv.y, yv.z, yv.w};
        float zz[4] = {zv.x, zv.y, zv.z, zv.w};
#pragma unroll
        for (int e = 0; e < 4; ++e) {
            const int k = k4 * 4 + e;
            float4 t0 = *(const float4*)&Ts[k][jb];
            float4 t1 = *(const float4*)&Ts[k][jb + 4];
            float tt[8] = {t0.x, t0.y, t0.z, t0.w, t1.x, t1.y, t1.z, t1.w};
#pragma unroll
            for (int q = 0; q < 8; ++q) {
                ay[q] = fmaf(yy[e], tt[q], ay[q]);
                az[q] = fmaf(zz[e], tt[q], az[q]);
            }
        }
    }
    float4 yc0 = *(const float4*)&Ys[i][J0 + jb];
    float4 yc1 = *(const float4*)&Ys[i][J0 + jb + 4];
    float4 zc0 = *(const float4*)&Zs[i][J0 + jb];
    float4 zc1 = *(const float4*)&Zs[i][J0 + jb + 4];
    float* Yo = Yout + (size_t)g * GD * GD + (size_t)i * GD + J0 + jb;
    float* Zo = Zout + (size_t)g * GD * GD + (size_t)i * GD + J0 + jb;
    *(float4*)(Yo)     = make_float4(1.5f*yc0.x - 0.5f*ay[0], 1.5f*yc0.y - 0.5f*ay[1],
                                     1.5f*yc0.z - 0.5f*ay[2], 1.5f*yc0.w - 0.5f*ay[3]);
    *(float4*)(Yo + 4) = make_float4(1.5f*yc1.x - 0.5f*ay[4], 1.5f*yc1.y - 0.5f*ay[5],
                                     1.5f*yc1.z - 0.5f*ay[6], 1.5f*yc1.w - 0.5f*ay[7]);
    *(float4*)(Zo)     = make_float4(1.5f*zc0.x - 0.5f*az[0], 1.5f*zc0.y - 0.5f*az[1],
                                     1.5f*zc0.z - 0.5f*az[2], 1.5f*zc0.w - 0.5f*az[3]);
    *(float4*)(Zo + 4) = make_float4(1.5f*zc1.x - 0.5f*az[4], 1.5f*zc1.y - 0.5f*az[5],
                                     1.5f*zc1.z - 0.5f*az[6], 1.5f*zc1.w - 0.5f*az[7]);
}

// ---------------- K5: out = (x - mu) * (Z / sqrt(c)) ---------------------------
__global__ __launch_bounds__(512) void k_apply(
    const float* __restrict__ x, const float* __restrict__ Zfin,
    const float* __restrict__ mean, const float* __restrict__ scale,
    float* __restrict__ out)
{
    __shared__ float Ws[128][132];
    __shared__ float Xs[128][132];
    const int bid = blockIdx.x;
    const int g = bid >> 4;
    const int rb = bid & 15;
    const int t = threadIdx.x;
    const float sc = scale[g];
    const float* Zg = Zfin + (size_t)g * GD * GD;
#pragma unroll
    for (int k = 0; k < 8; ++k) {
        int q = t + 512 * k;
        int row = q >> 5, c4i = q & 31;
        float4 v = *(const float4*)(Zg + (size_t)q * 4);
        v.x *= sc; v.y *= sc; v.z *= sc; v.w *= sc;
        *(float4*)&Ws[row][c4i * 4] = v;
    }
    const int c4 = t & 31;
    const float4 mu4 = *(const float4*)(mean + g * GD + c4 * 4);
    const int tx = t & 15, ty = t >> 4;
    const float* xb = x + (size_t)rb * 1024 * NCOLS + g * GD;
    float* ob = out + (size_t)rb * 1024 * NCOLS + g * GD;

    for (int chunk = 0; chunk < 8; ++chunk) {
        __syncthreads();
#pragma unroll
        for (int k = 0; k < 8; ++k) {
            int q = t + 512 * k;
            int row = q >> 5;  // 0..127
            float4 v = *(const float4*)(xb + (size_t)(chunk * 128 + row) * NCOLS + c4 * 4);
            v.x -= mu4.x; v.y -= mu4.y; v.z -= mu4.z; v.w -= mu4.w;
            *(float4*)&Xs[row][c4 * 4] = v;
        }
        __syncthreads();
        float acc[4][8];
#pragma unroll
        for (int r = 0; r < 4; ++r)
#pragma unroll
            for (int c = 0; c < 8; ++c) acc[r][c] = 0.f;
        for (int k4 = 0; k4 < 32; ++k4) {
            float4 xr[4];
#pragma unroll
            for (int r = 0; r < 4; ++r) xr[r] = *(const float4*)&Xs[ty * 4 + r][k4 * 4];
            float xa[4][4];
#pragma unroll
            for (int r = 0; r < 4; ++r) {
                xa[r][0] = xr[r].x; xa[r][1] = xr[r].y; xa[r][2] = xr[r].z; xa[r][3] = xr[r].w;
            }
#pragma unroll
            for (int e = 0; e < 4; ++e) {
                float4 w0 = *(const float4*)&Ws[k4 * 4 + e][tx * 8];
                float4 w1 = *(const float4*)&Ws[k4 * 4 + e][tx * 8 + 4];
                float wb[8] = {w0.x, w0.y, w0.z, w0.w, w1.x, w1.y, w1.z, w1.w};
#pragma unroll
                for (int r = 0; r < 4; ++r)
#pragma unroll
                    for (int c = 0; c < 8; ++c) acc[r][c] = fmaf(xa[r][e], wb[c], acc[r][c]);
            }
        }
#pragma unroll
        for (int r = 0; r < 4; ++r) {
            int row = chunk * 128 + ty * 4 + r;
            *(float4*)(ob + (size_t)row * NCOLS + tx * 8) =
                make_float4(acc[r][0], acc[r][1], acc[r][2], acc[r][3]);
            *(float4*)(ob + (size_t)row * NCOLS + tx * 8 + 4) =
                make_float4(acc[r][4], acc[r][5], acc[r][6], acc[r][7]);
        }
    }
}

extern "C" void kernel_launch(void* const* d_in, const int* in_sizes, int n_in,
                              void* d_out, int out_size, void* d_ws, size_t ws_size,
                              hipStream_t stream) {
    const float* x = (const float*)d_in[0];
    float* out = (float*)d_out;
    float* ws = (float*)d_ws;

    float* xtx    = ws;                        // 32*8*128*128 = 4,194,304 floats
    float* colsum = xtx + (size_t)NG * NP * GD * GD;   // 32,768
    float* mean   = colsum + (size_t)NG * NP * GD;     // 4,096
    float* scale  = mean + NCOLS;                      // 32
    float* Ya     = scale + 32;                        // 524,288 each
    float* Za     = Ya + (size_t)NG * GD * GD;
    float* Yb     = Za + (size_t)NG * GD * GD;
    float* Zb     = Yb + (size_t)NG * GD * GD;

    k_cov_partial<<<NG * NP, 512, 0, stream>>>(x, xtx, colsum);
    k_covprep<<<NG, 256, 0, stream>>>(xtx, colsum, mean, scale, Ya, Za);
    for (int it = 0; it < 6; ++it) {
        if ((it & 1) == 0)
            k_ns_iter<<<NG * 8, 256, 0, stream>>>(Ya, Za, Yb, Zb);
        else
            k_ns_iter<<<NG * 8, 256, 0, stream>>>(Yb, Zb, Ya, Za);
    }
    // 6 iterations (even) -> final Z in Za
    k_apply<<<NG * 16, 512, 0, stream>>>(x, Za, mean, scale, out);
}

// Round 2
// 486.419 us; speedup vs baseline: 1.1909x; 1.1909x over previous
//
#include <hip/hip_runtime.h>
#include <cstddef>

#define NROWS 16384
#define NCOLS 4096
#define NG 32
#define GD 128
#define NPC 16              // cov partials per group

typedef float f32x4 __attribute__((ext_vector_type(4)));
typedef short bf16x8 __attribute__((ext_vector_type(8)));

__device__ inline unsigned short f2bf(float f) {
    unsigned int u = __builtin_bit_cast(unsigned int, f);
    u += 0x7fffu + ((u >> 16) & 1u);
    return (unsigned short)(u >> 16);
}
__device__ inline float bf2f(unsigned short h) {
    unsigned int u = ((unsigned int)h) << 16;
    return __builtin_bit_cast(float, u);
}

// ============ K1: bf16 MFMA partial X^T X + fp32 column sums ==================
// grid 512 = 32 groups x 16 stripes; 256 thr (4 waves); 1024 rows/block.
__global__ __launch_bounds__(256) void k_cov(
    const float* __restrict__ x, float* __restrict__ xtx, float* __restrict__ colsum)
{
    __shared__ unsigned short xt[2][128][40];   // [feat][k-row] bf16, 80B rows
    __shared__ float red[4][128];
    const int bid = blockIdx.x;
    const int g = bid >> 4, p = bid & 15;
    const int t = threadIdx.x;
    const int f2 = t & 63;          // feature pair 0..63
    const int rh = t >> 6;          // row-eighth (== wave id)
    const int w = t >> 6;
    const int lane = t & 63;
    const int lm = lane & 15, lk = lane >> 4;
    const float* xb = x + (size_t)(p * 1024) * NCOLS + g * GD + 2 * f2;

    float csum0 = 0.f, csum1 = 0.f;
    f32x4 acc[2][8];
#pragma unroll
    for (int mi = 0; mi < 2; ++mi)
#pragma unroll
        for (int ni = 0; ni < 8; ++ni) acc[mi][ni] = (f32x4){0.f, 0.f, 0.f, 0.f};

    float2 v[8];
#define COV_LOAD(CC) \
    _Pragma("unroll") for (int i = 0; i < 8; ++i) \
        v[i] = *(const float2*)(xb + (size_t)((CC) * 32 + rh * 8 + i) * NCOLS);
#define COV_WRITE(BUF) { \
    bf16x8 h0, h1; \
    _Pragma("unroll") for (int i = 0; i < 8; ++i) { \
        csum0 += v[i].x; csum1 += v[i].y; \
        h0[i] = (short)f2bf(v[i].x); h1[i] = (short)f2bf(v[i].y); } \
    *(bf16x8*)&xt[BUF][2 * f2][rh * 8] = h0; \
    *(bf16x8*)&xt[BUF][2 * f2 + 1][rh * 8] = h1; }

    COV_LOAD(0);
    COV_WRITE(0);
    __syncthreads();

    for (int c = 0; c < 32; ++c) {
        const int cur = c & 1;
        if (c < 31) { COV_LOAD(c + 1); }
        bf16x8 frag[8];
#pragma unroll
        for (int fb = 0; fb < 8; ++fb)
            frag[fb] = *(const bf16x8*)&xt[cur][fb * 16 + lm][lk * 8];
#pragma unroll
        for (int mi = 0; mi < 2; ++mi)
#pragma unroll
            for (int ni = 0; ni < 8; ++ni)
                acc[mi][ni] = __builtin_amdgcn_mfma_f32_16x16x32_bf16(
                    frag[w * 2 + mi], frag[ni], acc[mi][ni], 0, 0, 0);
        if (c < 31) { COV_WRITE(cur ^ 1); }
        __syncthreads();
    }
#undef COV_LOAD
#undef COV_WRITE

    // partial C write: C/D layout col=lane&15, row=(lane>>4)*4+reg
    float* ob = xtx + (size_t)bid * (GD * GD);
#pragma unroll
    for (int mi = 0; mi < 2; ++mi)
#pragma unroll
        for (int ni = 0; ni < 8; ++ni) {
            const int i0 = (w * 2 + mi) * 16 + lk * 4;
            const int j = ni * 16 + lm;
#pragma unroll
            for (int r = 0; r < 4; ++r)
                ob[(size_t)(i0 + r) * GD + j] = acc[mi][ni][r];
        }
    // column-sum reduce
    red[rh][2 * f2] = csum0;
    red[rh][2 * f2 + 1] = csum1;
    __syncthreads();
    if (t < 128) {
        float s = 0.f;
#pragma unroll
        for (int r = 0; r < 4; ++r) s += red[r][t];
        colsum[(size_t)bid * GD + t] = s;
    }
}

// ============ K2: reduce partials -> C (mean-corrected) =======================
// grid 512 = 32 groups x 16 slices; 256 thr; 1024 elems/block.
__global__ __launch_bounds__(256) void k_covreduce(
    const float* __restrict__ xtx, const float* __restrict__ colsum,
    float* __restrict__ C, float* __restrict__ mean)
{
    __shared__ float mu[128];
    const int bid = blockIdx.x;
    const int g = bid >> 4, s = bid & 15;
    const int t = threadIdx.x;
    if (t < 128) {
        float m = 0.f;
#pragma unroll
        for (int p = 0; p < NPC; ++p) m += colsum[(size_t)(g * NPC + p) * GD + t];
        m *= (1.0f / (float)NROWS);
        mu[t] = m;
        if (s == 0) mean[g * GD + t] = m;
    }
    __syncthreads();
    const int e = s * 1024 + t * 4;
    const int i = e >> 7, j = e & 127;
    float4 sum = make_float4(0.f, 0.f, 0.f, 0.f);
#pragma unroll
    for (int p = 0; p < NPC; ++p) {
        const float4 vv = *(const float4*)(xtx + ((size_t)(g * NPC + p) << 14) + e);
        sum.x += vv.x; sum.y += vv.y; sum.z += vv.z; sum.w += vv.w;
    }
    const float inv = 1.0f / (float)(NROWS - 1);
    const float mi2 = (float)NROWS * mu[i];
    float4 r;
    r.x = (sum.x - mi2 * mu[j + 0]) * inv;
    r.y = (sum.y - mi2 * mu[j + 1]) * inv;
    r.z = (sum.z - mi2 * mu[j + 2]) * inv;
    r.w = (sum.w - mi2 * mu[j + 3]) * inv;
    *(float4*)(C + (size_t)g * (GD * GD) + e) = r;
}

// ============ K3: Gershgorin scale + Y0/Z0 ====================================
__global__ __launch_bounds__(256) void k_prep(
    const float* __restrict__ Cg, float* __restrict__ scale,
    float* __restrict__ Y0, float* __restrict__ Z0)
{
    __shared__ float Cs[128][129];
    __shared__ float rs[128];
    __shared__ float sinv[1];
    const int g = blockIdx.x;
    const int t = threadIdx.x;
    for (int k = 0; k < 64; ++k) {
        int e = t + 256 * k;
        Cs[e >> 7][e & 127] = Cg[(size_t)g * (GD * GD) + e];
    }
    __syncthreads();
    if (t < 128) {
        float s = 0.f;
        for (int i = 0; i < 128; ++i) s += fabsf(Cs[i][t]);
        rs[t] = s;
    }
    __syncthreads();
    if (t == 0) {
        float up = 0.f, lo = 1e30f;
        for (int i = 0; i < 128; ++i) {
            up = fmaxf(up, rs[i]);
            lo = fminf(lo, 2.0f * Cs[i][i] - rs[i]);
        }
        float c = 0.5f * (up + fmaxf(lo, 0.0f));
        c = fmaxf(c, 1e-20f);
        sinv[0] = 1.0f / c;
        scale[g] = rsqrtf(c);
    }
    __syncthreads();
    const float invc = sinv[0];
    for (int k = 0; k < 64; ++k) {
        int e = t + 256 * k;
        int i = e >> 7, j = e & 127;
        Y0[(size_t)g * (GD * GD) + e] = Cs[i][j] * invc;
        Z0[(size_t)g * (GD * GD) + e] = (i == j) ? 1.0f : 0.0f;
    }
}

// ============ K4: Newton-Schulz iteration (unchanged, fp32) ===================
__global__ __launch_bounds__(256) void k_ns_iter(
    const float* __restrict__ Yin, const float* __restrict__ Zin,
    float* __restrict__ Yout, float* __restrict__ Zout)
{
    __shared__ float Ys[128][132];
    __shared__ float Zs[128][132];
    __shared__ float Ts[128][16];
    const int bid = blockIdx.x;
    const int g = bid >> 3;
    const int sl = bid & 7;
    const int J0 = sl * 16;
    const int t = threadIdx.x;
    const float* Yg = Yin + (size_t)g * GD * GD;
    const float* Zg = Zin + (size_t)g * GD * GD;
#pragma unroll
    for (int k = 0; k < 16; ++k) {
        int q = t + 256 * k;
        int row = q >> 5, c4 = q & 31;
        *(float4*)&Ys[row][c4 * 4] = *(const float4*)(Yg + (size_t)q * 4);
        *(float4*)&Zs[row][c4 * 4] = *(const float4*)(Zg + (size_t)q * 4);
    }
    __syncthreads();
    const int i = t >> 1;
    const int jb = (t & 1) * 8;

    float accT[8];
#pragma unroll
    for (int q = 0; q < 8; ++q) accT[q] = 0.f;
    for (int k4 = 0; k4 < 32; ++k4) {
        float4 zv = *(const float4*)&Zs[i][k4 * 4];
        float zz[4] = {zv.x, zv.y, zv.z, zv.w};
#pragma unroll
        for (int e = 0; e < 4; ++e) {
            const int k = k4 * 4 + e;
            float4 y0 = *(const float4*)&Ys[k][J0 + jb];
            float4 y1 = *(const float4*)&Ys[k][J0 + jb + 4];
            float yy[8] = {y0.x, y0.y, y0.z, y0.w, y1.x, y1.y, y1.z, y1.w};
#pragma unroll
            for (int q = 0; q < 8; ++q) accT[q] = fmaf(zz[e], yy[q], accT[q]);
        }
    }
#pragma unroll
    for (int q = 0; q < 8; ++q) Ts[i][jb + q] = accT[q];
    __syncthreads();

    float ay[8], az[8];
#pragma unroll
    for (int q = 0; q < 8; ++q) { ay[q] = 0.f; az[q] = 0.f; }
    for (int k4 = 0; k4 < 32; ++k4) {
        float4 yv = *(const float4*)&Ys[i][k4 * 4];
        float4 zv = *(const float4*)&Zs[i][k4 * 4];
        float yy[4] = {yv.x, yv.y, yv.z, yv.w};
        float zz[4] = {zv.x, zv.y, zv.z, zv.w};
#pragma unroll
        for (int e = 0; e < 4; ++e) {
            const int k = k4 * 4 + e;
            float4 t0 = *(const float4*)&Ts[k][jb];
            float4 t1 = *(const float4*)&Ts[k][jb + 4];
            float tt[8] = {t0.x, t0.y, t0.z, t0.w, t1.x, t1.y, t1.z, t1.w};
#pragma unroll
            for (int q = 0; q < 8; ++q) {
                ay[q] = fmaf(yy[e], tt[q], ay[q]);
                az[q] = fmaf(zz[e], tt[q], az[q]);
            }
        }
    }
    float4 yc0 = *(const float4*)&Ys[i][J0 + jb];
    float4 yc1 = *(const float4*)&Ys[i][J0 + jb + 4];
    float4 zc0 = *(const float4*)&Zs[i][J0 + jb];
    float4 zc1 = *(const float4*)&Zs[i][J0 + jb + 4];
    float* Yo = Yout + (size_t)g * GD * GD + (size_t)i * GD + J0 + jb;
    float* Zo = Zout + (size_t)g * GD * GD + (size_t)i * GD + J0 + jb;
    *(float4*)(Yo)     = make_float4(1.5f*yc0.x - 0.5f*ay[0], 1.5f*yc0.y - 0.5f*ay[1],
                                     1.5f*yc0.z - 0.5f*ay[2], 1.5f*yc0.w - 0.5f*ay[3]);
    *(float4*)(Yo + 4) = make_float4(1.5f*yc1.x - 0.5f*ay[4], 1.5f*yc1.y - 0.5f*ay[5],
                                     1.5f*yc1.z - 0.5f*ay[6], 1.5f*yc1.w - 0.5f*ay[7]);
    *(float4*)(Zo)     = make_float4(1.5f*zc0.x - 0.5f*az[0], 1.5f*zc0.y - 0.5f*az[1],
                                     1.5f*zc0.z - 0.5f*az[2], 1.5f*zc0.w - 0.5f*az[3]);
    *(float4*)(Zo + 4) = make_float4(1.5f*zc1.x - 0.5f*az[4], 1.5f*zc1.y - 0.5f*az[5],
                                     1.5f*zc1.z - 0.5f*az[6], 1.5f*zc1.w - 0.5f*az[7]);
}

// ============ K5: WT[g][n][k] = (Z * rsqrt(c))^T as bf16 ======================
__global__ __launch_bounds__(256) void k_wprep(
    const float* __restrict__ Z, const float* __restrict__ scale,
    unsigned short* __restrict__ WT)
{
    __shared__ float Zs[128][129];
    const int g = blockIdx.x;
    const int t = threadIdx.x;
    const float sc = scale[g];
    for (int k = 0; k < 64; ++k) {
        int e = t + 256 * k;
        Zs[e >> 7][e & 127] = Z[(size_t)g * (GD * GD) + e];
    }
    __syncthreads();
    const int n = t & 127, kh = t >> 7;
    unsigned short* o = WT + (size_t)g * (GD * GD) + (size_t)n * GD + kh * 64;
    for (int k = 0; k < 64; k += 2) {
        unsigned int pk = (unsigned int)f2bf(Zs[kh * 64 + k][n] * sc)
                        | ((unsigned int)f2bf(Zs[kh * 64 + k + 1][n] * sc) << 16);
        *(unsigned int*)(o + k) = pk;
    }
}

// ============ K6: out = (x - mu) * Whi via hi/lo bf16 MFMA (K=256) ============
// grid 2048 = 32 groups x 64 row-blocks; 256 thr (4 waves); 256 rows/block.
__global__ __launch_bounds__(256) void k_apply(
    const float* __restrict__ x, const unsigned short* __restrict__ WT,
    const float* __restrict__ mean, float* __restrict__ out)
{
    __shared__ unsigned short Xs[2][64][264];   // [row][hi(128)|lo(128)] bf16
    const int bid = blockIdx.x;
    const int g = bid >> 6, rb = bid & 63;
    const int t = threadIdx.x;
    const int lane = t & 63, w = t >> 6;
    const int lm = lane & 15, lk = lane >> 4;
    const int f4 = t & 31, rq = t >> 5;
    const int row0 = rb * 256;
    const int nh = w >> 1;                      // n-half (64 cols)
    const int m0w = (w & 1) * 32;               // m-offset within 64-row chunk

    // hoist W fragments (B operand) into registers: 4 n-blocks x 4 k-steps
    bf16x8 Wf[4][4];
    {
        const unsigned short* wg = WT + (size_t)g * (GD * GD);
#pragma unroll
        for (int ni = 0; ni < 4; ++ni)
#pragma unroll
            for (int ks = 0; ks < 4; ++ks)
                Wf[ni][ks] = *(const bf16x8*)(wg
                    + (size_t)(nh * 64 + ni * 16 + lm) * GD + ks * 32 + lk * 8);
    }
    const float4 mu4 = *(const float4*)(mean + g * GD + f4 * 4);
    const float* xb = x + (size_t)row0 * NCOLS + g * GD + f4 * 4;

    float4 v[8];
#define APP_LOAD(CC) \
    _Pragma("unroll") for (int i = 0; i < 8; ++i) \
        v[i] = *(const float4*)(xb + (size_t)((CC) * 64 + rq * 8 + i) * NCOLS);
#define APP_WRITE(BUF) \
    _Pragma("unroll") for (int i = 0; i < 8; ++i) { \
        float cx = v[i].x - mu4.x, cy = v[i].y - mu4.y; \
        float cz = v[i].z - mu4.z, cw = v[i].w - mu4.w; \
        unsigned short hx = f2bf(cx), hy = f2bf(cy), hz = f2bf(cz), hw = f2bf(cw); \
        unsigned int h01 = (unsigned int)hx | ((unsigned int)hy << 16); \
        unsigned int h23 = (unsigned int)hz | ((unsigned int)hw << 16); \
        unsigned int l01 = (unsigned int)f2bf(cx - bf2f(hx)) \
                         | ((unsigned int)f2bf(cy - bf2f(hy)) << 16); \
        unsigned int l23 = (unsigned int)f2bf(cz - bf2f(hz)) \
                         | ((unsigned int)f2bf(cw - bf2f(hw)) << 16); \
        *(uint2*)&Xs[BUF][rq * 8 + i][f4 * 4] = make_uint2(h01, h23); \
        *(uint2*)&Xs[BUF][rq * 8 + i][128 + f4 * 4] = make_uint2(l01, l23); }

    APP_LOAD(0);
    APP_WRITE(0);
    __syncthreads();

    for (int c = 0; c < 4; ++c) {
        const int cur = c & 1;
        if (c < 3) { APP_LOAD(c + 1); }
        f32x4 acc[2][4];
#pragma unroll
        for (int mi = 0; mi < 2; ++mi)
#pragma unroll
            for (int ni = 0; ni < 4; ++ni) acc[mi][ni] = (f32x4){0.f, 0.f, 0.f, 0.f};
#pragma unroll
        for (int ks = 0; ks < 8; ++ks) {
            bf16x8 a0 = *(const bf16x8*)&Xs[cur][m0w + lm][ks * 32 + lk * 8];
            bf16x8 a1 = *(const bf16x8*)&Xs[cur][m0w + 16 + lm][ks * 32 + lk * 8];
#pragma unroll
            for (int ni = 0; ni < 4; ++ni) {
                acc[0][ni] = __builtin_amdgcn_mfma_f32_16x16x32_bf16(
                    a0, Wf[ni][ks & 3], acc[0][ni], 0, 0, 0);
                acc[1][ni] = __builtin_amdgcn_mfma_f32_16x16x32_bf16(
                    a1, Wf[ni][ks & 3], acc[1][ni], 0, 0, 0);
            }
        }
        // epilogue: C/D layout col=lane&15, row=(lane>>4)*4+reg
        float* ob = out + (size_t)(row0 + c * 64 + m0w) * NCOLS + g * GD + nh * 64;
#pragma unroll
        for (int mi = 0; mi < 2; ++mi)
#pragma unroll
            for (int ni = 0; ni < 4; ++ni)
#pragma unroll
                for (int r = 0; r < 4; ++r)
                    ob[(size_t)(mi * 16 + lk * 4 + r) * NCOLS + ni * 16 + lm]
                        = acc[mi][ni][r];
        if (c < 3) { APP_WRITE(cur ^ 1); }
        __syncthreads();
    }
#undef APP_LOAD
#undef APP_WRITE
}

extern "C" void kernel_launch(void* const* d_in, const int* in_sizes, int n_in,
                              void* d_out, int out_size, void* d_ws, size_t ws_size,
                              hipStream_t stream) {
    const float* x = (const float*)d_in[0];
    float* out = (float*)d_out;
    float* ws = (float*)d_ws;

    float* xtx    = ws;                                  // 512*16384 = 8,388,608
    float* colsum = xtx + (size_t)NG * NPC * GD * GD;    // 65,536
    float* mean   = colsum + (size_t)NG * NPC * GD;      // 4,096
    float* scale  = mean + NCOLS;                        // 32
    float* Cbuf   = scale + 32;                          // 524,288
    float* Ya     = Cbuf + (size_t)NG * GD * GD;
    float* Za     = Ya + (size_t)NG * GD * GD;
    float* Yb     = Za + (size_t)NG * GD * GD;
    float* Zb     = Yb + (size_t)NG * GD * GD;
    unsigned short* WT = (unsigned short*)(Zb + (size_t)NG * GD * GD);

    k_cov<<<NG * NPC, 256, 0, stream>>>(x, xtx, colsum);
    k_covreduce<<<NG * NPC, 256, 0, stream>>>(xtx, colsum, Cbuf, mean);
    k_prep<<<NG, 256, 0, stream>>>(Cbuf, scale, Ya, Za);
    for (int it = 0; it < 6; ++it) {
        if ((it & 1) == 0)
            k_ns_iter<<<NG * 8, 256, 0, stream>>>(Ya, Za, Yb, Zb);
        else
            k_ns_iter<<<NG * 8, 256, 0, stream>>>(Yb, Zb, Ya, Za);
    }
    k_wprep<<<NG, 256, 0, stream>>>(Za, scale, WT);
    k_apply<<<NG * 64, 256, 0, stream>>>(x, WT, mean, out);
}